// Round 9
// baseline (1088.752 us; speedup 1.0000x reference)
//
#include <hip/hip_runtime.h>

constexpr int Bn  = 4;
constexpr int Tn  = 2048;
constexpr int Sn  = 2048;
constexpr int Dn  = 512;
constexpr int Hn  = 8;
constexpr int DKn = 64;
constexpr int DVn = 64;
constexpr int HDn = 512;   // H*DK = H*DV
constexpr int SKn = 30;    // sample_k
constexpr int Un  = 30;    // top-u
constexpr int Gu  = 6;     // u's per attention block
constexpr int NGroups = Un / Gu;            // 5
constexpr int NAttnG  = Bn * Hn * NGroups;  // 160 attention blocks
constexpr int RowSplit = 57344;             // fscores rows filled in megaA
constexpr int NGemm  = 768;
constexpr int NFillA = RowSplit / 4;                      // 14336
constexpr int NSm    = (Bn * Tn) / 4;                     // 2048 (wave per t)
constexpr int NTail2 = (Bn * Hn * Tn - RowSplit) / 4;     // 2048
constexpr int NOutF  = (Bn * Tn) / 8;                     // 1024
constexpr float kScale = 0.125f;            // 1/sqrt(DK)

constexpr int BM = 128, BN = 128, BK = 16;

// ------------- dispatch 1: blocks[0..767] fused q/k/v GEMM; rest fill fscores rows [0,57344) -------------
__global__ __launch_bounds__(256) void gemm_fill_kernel(
    const float* __restrict__ xq, const float* __restrict__ xk, const float* __restrict__ xv,
    const float* __restrict__ Wq, const float* __restrict__ Wk, const float* __restrict__ Wv,
    const float* __restrict__ bq, const float* __restrict__ bk, const float* __restrict__ bv,
    float* __restrict__ qo, float* __restrict__ ko, float* __restrict__ vo,
    float* __restrict__ fscores) {
  __shared__ float As[BK][BM + 4];
  __shared__ float Bs[BK][BN];
  const int bid = blockIdx.x;
  const int tid = threadIdx.x;

  if (bid >= NGemm) {
    const size_t r0 = (size_t)(bid - NGemm) * 4;
    const float c = 1.0f / Sn;
    const float4 c4v = make_float4(c, c, c, c);
    float4* fs4 = (float4*)fscores + r0 * (Sn / 4);
#pragma unroll
    for (int i = 0; i < 8; ++i) fs4[i * 256 + tid] = c4v;
    return;
  }

  const int z = bid >> 8;            // 0..2 selects q/k/v
  const int rem = bid & 255;
  const float* X = (z == 0) ? xq : (z == 1) ? xk : xv;
  const float* W = (z == 0) ? Wq : (z == 1) ? Wk : Wv;
  const float* bias = (z == 0) ? bq : (z == 1) ? bk : bv;
  float* Y = (z == 0) ? qo : (z == 1) ? ko : vo;
  const int N = HDn, K = Dn;

  const int bn = (rem & 3) * BN;
  const int bm = (rem >> 2) * BM;
  const int tx = tid & 15;
  const int ty = tid >> 4;
  const int arow = tid >> 2;
  const int ac4  = (tid & 3) << 2;
  const int brow = tid >> 5;
  const int bc4  = (tid & 31) << 2;

  float acc[8][8];
#pragma unroll
  for (int i = 0; i < 8; ++i)
#pragma unroll
    for (int j = 0; j < 8; ++j) acc[i][j] = 0.f;

  for (int k0 = 0; k0 < K; k0 += BK) {
    float4 a0 = *(const float4*)(X + (size_t)(bm + arow) * K + k0 + ac4);
    float4 a1 = *(const float4*)(X + (size_t)(bm + arow + 64) * K + k0 + ac4);
    float4 b0 = *(const float4*)(W + (size_t)(k0 + brow) * N + bn + bc4);
    float4 b1 = *(const float4*)(W + (size_t)(k0 + brow + 8) * N + bn + bc4);
    __syncthreads();
    As[ac4 + 0][arow] = a0.x; As[ac4 + 1][arow] = a0.y;
    As[ac4 + 2][arow] = a0.z; As[ac4 + 3][arow] = a0.w;
    As[ac4 + 0][arow + 64] = a1.x; As[ac4 + 1][arow + 64] = a1.y;
    As[ac4 + 2][arow + 64] = a1.z; As[ac4 + 3][arow + 64] = a1.w;
    *(float4*)&Bs[brow][bc4] = b0;
    *(float4*)&Bs[brow + 8][bc4] = b1;
    __syncthreads();
#pragma unroll
    for (int kk = 0; kk < BK; ++kk) {
      float a[8], b[8];
      *(float4*)&a[0] = *(const float4*)&As[kk][ty * 8];
      *(float4*)&a[4] = *(const float4*)&As[kk][ty * 8 + 4];
      *(float4*)&b[0] = *(const float4*)&Bs[kk][tx * 8];
      *(float4*)&b[4] = *(const float4*)&Bs[kk][tx * 8 + 4];
#pragma unroll
      for (int i = 0; i < 8; ++i)
#pragma unroll
        for (int j = 0; j < 8; ++j) acc[i][j] = fmaf(a[i], b[j], acc[i][j]);
    }
  }
  float bb[8];
#pragma unroll
  for (int j = 0; j < 8; ++j) bb[j] = bias[bn + tx * 8 + j];
#pragma unroll
  for (int i = 0; i < 8; ++i) {
    const int row = bm + ty * 8 + i;
    float4 o0 = make_float4(acc[i][0] + bb[0], acc[i][1] + bb[1],
                            acc[i][2] + bb[2], acc[i][3] + bb[3]);
    float4 o1 = make_float4(acc[i][4] + bb[4], acc[i][5] + bb[5],
                            acc[i][6] + bb[6], acc[i][7] + bb[7]);
    *(float4*)(Y + (size_t)row * N + bn + tx * 8) = o0;
    *(float4*)(Y + (size_t)row * N + bn + tx * 8 + 4) = o1;
  }
}

// ------------- dispatch 2: [0,2048) sampled_m (wave/t); [2048,2052) vmean+base; [2052,4100) fscores tail fill -------------
__global__ __launch_bounds__(256) void sm_vmean_tail_kernel(
    const float* __restrict__ q, const float* __restrict__ k,
    const int* __restrict__ idxs, const float* __restrict__ v,
    const float* __restrict__ Wo, const float* __restrict__ bo,
    float* __restrict__ Mt, float* __restrict__ vmean, float* __restrict__ basep,
    float* __restrict__ fscores) {
  const int bid = blockIdx.x;
  const int tid = threadIdx.x;
  const int lane = tid & 63, w = tid >> 6;

  if (bid < NSm) {
    // sampled qk -> M; one wave per t; lanes = 4 j-rows x 16 d-lanes
    const int bt = bid * 4 + w;
    const int b = bt >> 11, t = bt & (Tn - 1);
    const int jq = lane >> 4;      // 0..3
    const int d16 = lane & 15;     // 0..15
    const int myidx = (lane < SKn) ? idxs[t * SKn + lane] : 0;
    const float* qrow = q + (size_t)bt * HDn;
    const float* kb = k + (size_t)b * Sn * HDn;
    for (int h = 0; h < Hn; ++h) {
      const float4 qv = *(const float4*)(qrow + h * DKn + d16 * 4);
      float mx = -1e30f, sum = 0.f;
#pragma unroll
      for (int jb = 0; jb < 32; jb += 4) {
        const int j = jb + jq;
        const int srow = __shfl(myidx, j);
        const float4 kv = *(const float4*)(kb + (size_t)srow * HDn + h * DKn + d16 * 4);
        float p = kv.x * qv.x + kv.y * qv.y + kv.z * qv.z + kv.w * qv.w;
        p += __shfl_xor(p, 1);
        p += __shfl_xor(p, 2);
        p += __shfl_xor(p, 4);
        p += __shfl_xor(p, 8);
        if (j < SKn) { mx = fmaxf(mx, p); sum += p; }
      }
      mx = fmaxf(mx, __shfl_xor(mx, 16));
      mx = fmaxf(mx, __shfl_xor(mx, 32));
      sum += __shfl_xor(sum, 16);
      sum += __shfl_xor(sum, 32);
      if (lane == 0) Mt[((size_t)(b * Hn + h)) * Tn + t] = mx - sum * (1.0f / SKn);
    }
    return;
  }

  if (bid < NSm + 4) {
    // vmean + base row for batch b
    __shared__ float4 part[256];
    __shared__ float vm[HDn];
    const int b = bid - NSm;
    const float4* v4 = (const float4*)(v + (size_t)b * Sn * HDn);
    const int c4 = tid & 127, half = tid >> 7;
    float4 acc = make_float4(0.f, 0.f, 0.f, 0.f);
    for (int s = half; s < Sn; s += 2) {
      const float4 x = v4[(size_t)s * 128 + c4];
      acc.x += x.x; acc.y += x.y; acc.z += x.z; acc.w += x.w;
    }
    part[tid] = acc;
    __syncthreads();
    if (half == 0) {
      float4 a = part[c4], bpp = part[128 + c4];
      const float sc = 1.0f / Sn;
      float4 r = make_float4((a.x + bpp.x) * sc, (a.y + bpp.y) * sc,
                             (a.z + bpp.z) * sc, (a.w + bpp.w) * sc);
      *(float4*)(vm + c4 * 4) = r;
      *(float4*)(vmean + b * HDn + c4 * 4) = r;
    }
    __syncthreads();
    const float4* Wo4 = (const float4*)Wo;
    float4 acc2 = make_float4(0.f, 0.f, 0.f, 0.f);
    for (int c = half * 256; c < half * 256 + 256; ++c) {
      const float vmc = vm[c];
      const float4 wrow = Wo4[(size_t)c * 128 + c4];
      acc2.x += vmc * wrow.x; acc2.y += vmc * wrow.y;
      acc2.z += vmc * wrow.z; acc2.w += vmc * wrow.w;
    }
    __syncthreads();
    part[tid] = acc2;
    __syncthreads();
    if (half == 0) {
      float4 a = part[c4], bpp = part[128 + c4];
      const float4 bb = ((const float4*)bo)[c4];
      float4 r = make_float4(a.x + bpp.x + bb.x, a.y + bpp.y + bb.y,
                             a.z + bpp.z + bb.z, a.w + bpp.w + bb.w);
      ((float4*)basep)[b * 128 + c4] = r;
    }
    return;
  }

  // fscores tail fill (rows [RowSplit, 65536)), unconditional — attn overwrites its rows later
  const int fid = bid - NSm - 4;              // 0..2047
  const size_t r = RowSplit + (size_t)fid * 4;
  const float c = 1.0f / Sn;
  const float4 c4v = make_float4(c, c, c, c);
  float4* fs4 = (float4*)fscores + r * (Sn / 4);
#pragma unroll
  for (int i = 0; i < 8; ++i) fs4[i * 256 + tid] = c4v;
}

// ------------- dispatch 3: [0,32) top-30 per (b,h); [32,1056) out-base fill (unconditional) -------------
__global__ __launch_bounds__(256) void topk_outfill_kernel(
    const float* __restrict__ Mt, const float* __restrict__ basep,
    int* __restrict__ top, float* __restrict__ out) {
  const int tid = threadIdx.x;
  const int lane = tid & 63, w = tid >> 6;

  if (blockIdx.x >= 32) {
    // out[b, t, :] = base[b, :], 8 rows per block
    const int fid = blockIdx.x - 32;            // 0..1023
    const int r0 = fid * 8;
    const int b = r0 >> 11;
    const int col4 = tid & 127, rh = tid >> 7;
    const float4 bv4 = ((const float4*)basep)[b * 128 + col4];
#pragma unroll
    for (int rp = 0; rp < 4; ++rp) {
      const int rr = rp * 2 + rh;
      *((float4*)(out + (size_t)(r0 + rr) * HDn) + col4) = bv4;
    }
    return;
  }

  __shared__ float vals[Tn];
  __shared__ float wv[4];
  __shared__ int wi[4];
  const int bh = blockIdx.x;
  for (int i = tid; i < Tn; i += 256) vals[i] = Mt[(size_t)bh * Tn + i];
  __syncthreads();
  for (int u = 0; u < Un; ++u) {
    float bv = -1e30f; int bi = 0x7fffffff;
    for (int i = tid; i < Tn; i += 256) {
      const float x = vals[i];
      if (x > bv) { bv = x; bi = i; }
    }
#pragma unroll
    for (int o = 1; o < 64; o <<= 1) {
      const float ov = __shfl_xor(bv, o);
      const int oi = __shfl_xor(bi, o);
      if (ov > bv || (ov == bv && oi < bi)) { bv = ov; bi = oi; }
    }
    if (lane == 0) { wv[w] = bv; wi[w] = bi; }
    __syncthreads();
    bv = wv[0]; bi = wi[0];
#pragma unroll
    for (int j = 1; j < 4; ++j) {
      if (wv[j] > bv || (wv[j] == bv && wi[j] < bi)) { bv = wv[j]; bi = wi[j]; }
    }
    if (tid == 0) { top[bh * Un + u] = bi; vals[bi] = -1e30f; }
    __syncthreads();
  }
}

// ------------- dispatch 4: grouped attention, Gu=6 u's per block -------------
__global__ __launch_bounds__(256) void attn_kernel(
    const float* __restrict__ q, const float* __restrict__ k,
    const float* __restrict__ v, const float* __restrict__ vmean,
    const int* __restrict__ top, const float* __restrict__ Wo,
    float* __restrict__ out, float* __restrict__ fscores) {
  const int tid = threadIdx.x;
  const int bid = blockIdx.x;
  const int grp = bid % NGroups;       // 0..4
  const int bh = bid / NGroups;        // 0..31
  const int h = bh & (Hn - 1), b = bh >> 3;
  const int u0 = grp * Gu;
  const int lane = tid & 63, w = tid >> 6;

  __shared__ float qs[Gu][DKn];        // reused later as delta
  __shared__ float sc[Gu][2052];       // padded: conflict-free column access
  __shared__ float red[8];
  __shared__ int tsel[Gu];
  __shared__ float4 partv[4][Gu][16];

  if (tid < Gu) tsel[tid] = top[bh * Un + u0 + tid];
  __syncthreads();
  for (int i = tid; i < Gu * DKn; i += 256) {
    const int g = i >> 6, d = i & 63;
    qs[g][d] = q[((size_t)(b * Tn + tsel[g])) * HDn + h * DKn + d];
  }
  __syncthreads();

  // phase 1: scores for all 6 u's, k row read once
  const float4* k4 = (const float4*)k;
  for (int s = tid; s < Sn; s += 256) {
    const float4* krow = k4 + ((size_t)(b * Sn + s)) * 128 + h * 16;
    float acc[Gu];
#pragma unroll
    for (int g = 0; g < Gu; ++g) acc[g] = 0.f;
#pragma unroll
    for (int d4i = 0; d4i < 16; ++d4i) {
      const float4 kv = krow[d4i];
#pragma unroll
      for (int g = 0; g < Gu; ++g) {
        const float4 qv = *(const float4*)&qs[g][d4i * 4];
        acc[g] += kv.x * qv.x + kv.y * qv.y + kv.z * qv.z + kv.w * qv.w;
      }
    }
#pragma unroll
    for (int g = 0; g < Gu; ++g) sc[g][s] = acc[g] * kScale;
  }
  __syncthreads();

  // phase 2: softmax per u
  float invs[Gu];
#pragma unroll
  for (int g = 0; g < Gu; ++g) {
    float lm = -1e30f;
    for (int i = tid; i < Sn; i += 256) lm = fmaxf(lm, sc[g][i]);
#pragma unroll
    for (int o = 1; o < 64; o <<= 1) lm = fmaxf(lm, __shfl_xor(lm, o));
    if (lane == 0) red[w] = lm;
    __syncthreads();
    const float mx = fmaxf(fmaxf(red[0], red[1]), fmaxf(red[2], red[3]));
    float ls = 0.f;
    for (int i = tid; i < Sn; i += 256) {
      const float e = __expf(sc[g][i] - mx);
      sc[g][i] = e;
      ls += e;
    }
#pragma unroll
    for (int o = 1; o < 64; o <<= 1) ls += __shfl_xor(ls, o);
    if (lane == 0) red[4 + w] = ls;
    __syncthreads();
    invs[g] = 1.0f / (red[4] + red[5] + red[6] + red[7]);
    __syncthreads();   // WAR on red[] before next g
  }
  // normalize + write fscores rows (overwrite the 1/S fill)
#pragma unroll
  for (int g = 0; g < Gu; ++g) {
    const float inv = invs[g];
    float4* scg4 = (float4*)sc[g];
    float4* fsrow4 = (float4*)(fscores + ((size_t)bh * Tn + tsel[g]) * Sn);
#pragma unroll
    for (int it = 0; it < 2; ++it) {
      const int i = it * 256 + tid;
      float4 p = scg4[i];
      p.x *= inv; p.y *= inv; p.z *= inv; p.w *= inv;
      scg4[i] = p;
      fsrow4[i] = p;
    }
  }
  __syncthreads();

  // phase 3: attn = scores @ v, v row read once
  const int d4 = lane & 15;
  const int sg = (w << 2) + (lane >> 4);   // 0..15
  const float4* v4 = (const float4*)v;
  float4 pacc[Gu];
#pragma unroll
  for (int g = 0; g < Gu; ++g) pacc[g] = make_float4(0.f, 0.f, 0.f, 0.f);
  for (int s = sg; s < Sn; s += 16) {
    const float4 vv = v4[((size_t)(b * Sn + s)) * 128 + h * 16 + d4];
#pragma unroll
    for (int g = 0; g < Gu; ++g) {
      const float p = sc[g][s];
      pacc[g].x += p * vv.x; pacc[g].y += p * vv.y;
      pacc[g].z += p * vv.z; pacc[g].w += p * vv.w;
    }
  }
#pragma unroll
  for (int g = 0; g < Gu; ++g) {
#pragma unroll
    for (int o = 16; o < 64; o <<= 1) {
      pacc[g].x += __shfl_xor(pacc[g].x, o);
      pacc[g].y += __shfl_xor(pacc[g].y, o);
      pacc[g].z += __shfl_xor(pacc[g].z, o);
      pacc[g].w += __shfl_xor(pacc[g].w, o);
    }
    if (lane < 16) partv[w][g][lane] = pacc[g];
  }
  __syncthreads();
  if (tid < Gu * 16) {
    const int g = tid >> 4, dd = tid & 15;
    float4 r = partv[0][g][dd];
    const float4 r1 = partv[1][g][dd], r2 = partv[2][g][dd], r3 = partv[3][g][dd];
    r.x += r1.x + r2.x + r3.x; r.y += r1.y + r2.y + r3.y;
    r.z += r1.z + r2.z + r3.z; r.w += r1.w + r2.w + r3.w;
    const float4 vm4 = ((const float4*)vmean)[bh * 16 + dd];
    r.x -= vm4.x; r.y -= vm4.y; r.z -= vm4.z; r.w -= vm4.w;
    *(float4*)&qs[g][dd * 4] = r;      // qs reused as delta
  }
  __syncthreads();

  // phase 4: out rows += delta @ Wo[h*64:(h+1)*64,:], 2 u's in parallel (adds onto stored base)
  const int col4 = tid & 127, gg = tid >> 7;
  const float4* Wo4 = (const float4*)Wo;
#pragma unroll
  for (int gp = 0; gp < Gu / 2; ++gp) {
    const int g = gp * 2 + gg;
    float4 a = make_float4(0.f, 0.f, 0.f, 0.f);
#pragma unroll
    for (int d = 0; d < DKn; ++d) {
      const float dv = qs[g][d];
      const float4 wrow = Wo4[(size_t)(h * DKn + d) * 128 + col4];
      a.x += dv * wrow.x; a.y += dv * wrow.y;
      a.z += dv * wrow.z; a.w += dv * wrow.w;
    }
    float* orow = out + ((size_t)(b * Tn + tsel[g])) * HDn + col4 * 4;
    atomicAdd(orow + 0, a.x); atomicAdd(orow + 1, a.y);
    atomicAdd(orow + 2, a.z); atomicAdd(orow + 3, a.w);
  }
}

extern "C" void kernel_launch(void* const* d_in, const int* in_sizes, int n_in,
                              void* d_out, int out_size, void* d_ws, size_t ws_size,
                              hipStream_t stream) {
  const float* x_q = (const float*)d_in[0];
  const float* x_k = (const float*)d_in[1];
  const float* x_v = (const float*)d_in[2];
  const float* Wq = (const float*)d_in[3];
  const float* bq = (const float*)d_in[4];
  const float* Wk = (const float*)d_in[5];
  const float* bk = (const float*)d_in[6];
  const float* Wv = (const float*)d_in[7];
  const float* bv = (const float*)d_in[8];
  const float* Wo = (const float*)d_in[9];
  const float* bo = (const float*)d_in[10];
  const int* idx = (const int*)d_in[11];

  float* out = (float*)d_out;
  float* fscores = out + (size_t)Bn * Tn * HDn;

  float* ws = (float*)d_ws;
  float* q = ws;
  float* kp = ws + (size_t)4194304;
  float* vp = ws + (size_t)8388608;
  float* Mt = ws + (size_t)12582912;
  float* vmean = ws + (size_t)12648448;
  float* basep = ws + (size_t)12650496;
  int* top = (int*)(ws + (size_t)12652544);

  // 1) fused q/k/v projections overlapped with most of the final_scores fill
  gemm_fill_kernel<<<NGemm + NFillA, 256, 0, stream>>>(
      x_q, x_k, x_v, Wq, Wk, Wv, bq, bk, bv, q, kp, vp, fscores);

  // 2) sampled scores + vmean/base + fscores tail fill
  sm_vmean_tail_kernel<<<NSm + 4 + NTail2, 256, 0, stream>>>(
      q, kp, idx, vp, Wo, bo, Mt, vmean, basep, fscores);

  // 3) top-30 per (b,h) + unconditional out-base fill
  topk_outfill_kernel<<<32 + NOutF, 256, 0, stream>>>(Mt, basep, top, out);

  // 4) grouped attention (overwrites its fscores rows; atomicAdds deltas onto base)
  attn_kernel<<<NAttnG, 256, 0, stream>>>(q, kp, vp, vmean, top, Wo, out, fscores);
}

// Round 10
// 1039.765 us; speedup vs baseline: 1.0471x; 1.0471x over previous
//
#include <hip/hip_runtime.h>

constexpr int Bn  = 4;
constexpr int Tn  = 2048;
constexpr int Sn  = 2048;
constexpr int Dn  = 512;
constexpr int Hn  = 8;
constexpr int DKn = 64;
constexpr int DVn = 64;
constexpr int HDn = 512;   // H*DK = H*DV
constexpr int SKn = 30;    // sample_k
constexpr int Un  = 30;    // top-u
constexpr int Gu  = 6;     // u's per attention block
constexpr int NGroups = Un / Gu;            // 5
constexpr int NAttnG  = Bn * Hn * NGroups;  // 160 attention blocks
constexpr int NOutF   = (Bn * Tn) / 8;      // 1024 out-base blocks (8 rows each)
constexpr int RowSplit = 57344;             // fscores rows filled in megaA
constexpr int NGemm  = 768;
constexpr int NFillA = RowSplit / 4;                      // 14336
constexpr int NTailF = (Bn * Hn * Tn - RowSplit) / 4;     // 2048
constexpr float kScale = 0.125f;            // 1/sqrt(DK)

constexpr int BM = 128, BN = 128, BK = 16;

// ------------- mega A: blocks[0..767] fused q/k/v GEMM; rest fill fscores rows [0,57344) -------------
__global__ __launch_bounds__(256) void gemm_fill_kernel(
    const float* __restrict__ xq, const float* __restrict__ xk, const float* __restrict__ xv,
    const float* __restrict__ Wq, const float* __restrict__ Wk, const float* __restrict__ Wv,
    const float* __restrict__ bq, const float* __restrict__ bk, const float* __restrict__ bv,
    float* __restrict__ qo, float* __restrict__ ko, float* __restrict__ vo,
    float* __restrict__ fscores) {
  __shared__ float As[BK][BM + 4];
  __shared__ float Bs[BK][BN];
  const int bid = blockIdx.x;
  const int tid = threadIdx.x;

  if (bid >= NGemm) {
    // fill 4 consecutive rows (32 KB contiguous) of final_scores with 1/S
    const size_t r0 = (size_t)(bid - NGemm) * 4;
    const float c = 1.0f / Sn;
    const float4 c4v = make_float4(c, c, c, c);
    float4* fs4 = (float4*)fscores + r0 * (Sn / 4);
#pragma unroll
    for (int i = 0; i < 8; ++i) fs4[i * 256 + tid] = c4v;
    return;
  }

  const int z = bid >> 8;            // 0..2 selects q/k/v
  const int rem = bid & 255;
  const float* X = (z == 0) ? xq : (z == 1) ? xk : xv;
  const float* W = (z == 0) ? Wq : (z == 1) ? Wk : Wv;
  const float* bias = (z == 0) ? bq : (z == 1) ? bk : bv;
  float* Y = (z == 0) ? qo : (z == 1) ? ko : vo;
  const int N = HDn, K = Dn;

  const int bn = (rem & 3) * BN;
  const int bm = (rem >> 2) * BM;
  const int tx = tid & 15;
  const int ty = tid >> 4;
  const int arow = tid >> 2;
  const int ac4  = (tid & 3) << 2;
  const int brow = tid >> 5;
  const int bc4  = (tid & 31) << 2;

  float acc[8][8];
#pragma unroll
  for (int i = 0; i < 8; ++i)
#pragma unroll
    for (int j = 0; j < 8; ++j) acc[i][j] = 0.f;

  for (int k0 = 0; k0 < K; k0 += BK) {
    float4 a0 = *(const float4*)(X + (size_t)(bm + arow) * K + k0 + ac4);
    float4 a1 = *(const float4*)(X + (size_t)(bm + arow + 64) * K + k0 + ac4);
    float4 b0 = *(const float4*)(W + (size_t)(k0 + brow) * N + bn + bc4);
    float4 b1 = *(const float4*)(W + (size_t)(k0 + brow + 8) * N + bn + bc4);
    __syncthreads();
    As[ac4 + 0][arow] = a0.x; As[ac4 + 1][arow] = a0.y;
    As[ac4 + 2][arow] = a0.z; As[ac4 + 3][arow] = a0.w;
    As[ac4 + 0][arow + 64] = a1.x; As[ac4 + 1][arow + 64] = a1.y;
    As[ac4 + 2][arow + 64] = a1.z; As[ac4 + 3][arow + 64] = a1.w;
    *(float4*)&Bs[brow][bc4] = b0;
    *(float4*)&Bs[brow + 8][bc4] = b1;
    __syncthreads();
#pragma unroll
    for (int kk = 0; kk < BK; ++kk) {
      float a[8], b[8];
      *(float4*)&a[0] = *(const float4*)&As[kk][ty * 8];
      *(float4*)&a[4] = *(const float4*)&As[kk][ty * 8 + 4];
      *(float4*)&b[0] = *(const float4*)&Bs[kk][tx * 8];
      *(float4*)&b[4] = *(const float4*)&Bs[kk][tx * 8 + 4];
#pragma unroll
      for (int i = 0; i < 8; ++i)
#pragma unroll
        for (int j = 0; j < 8; ++j) acc[i][j] = fmaf(a[i], b[j], acc[i][j]);
    }
  }
  float bb[8];
#pragma unroll
  for (int j = 0; j < 8; ++j) bb[j] = bias[bn + tx * 8 + j];
#pragma unroll
  for (int i = 0; i < 8; ++i) {
    const int row = bm + ty * 8 + i;
    float4 o0 = make_float4(acc[i][0] + bb[0], acc[i][1] + bb[1],
                            acc[i][2] + bb[2], acc[i][3] + bb[3]);
    float4 o1 = make_float4(acc[i][4] + bb[4], acc[i][5] + bb[5],
                            acc[i][6] + bb[6], acc[i][7] + bb[7]);
    *(float4*)(Y + (size_t)row * N + bn + tx * 8) = o0;
    *(float4*)(Y + (size_t)row * N + bn + tx * 8 + 4) = o1;
  }
}

// ------------- sampled qk -> M[b,h,t]; lanes = 4 j-rows x 16 d-lanes -------------
__global__ __launch_bounds__(64) void sampled_m_kernel(
    const float* __restrict__ q, const float* __restrict__ k,
    const int* __restrict__ idxs, float* __restrict__ Mt) {
  const int bt = blockIdx.x;
  const int b = bt >> 11, t = bt & (Tn - 1);
  const int lane = threadIdx.x;
  const int jq = lane >> 4;      // 0..3
  const int d16 = lane & 15;     // 0..15
  __shared__ int sidx[32];
  if (lane < SKn) sidx[lane] = idxs[t * SKn + lane];
  if (lane >= SKn && lane < 32) sidx[lane] = 0;
  __syncthreads();
  const float* qrow = q + (size_t)bt * HDn;
  const float* kb = k + (size_t)b * Sn * HDn;
  for (int h = 0; h < Hn; ++h) {
    const float4 qv = *(const float4*)(qrow + h * DKn + d16 * 4);
    float mx = -1e30f, sum = 0.f;
#pragma unroll
    for (int jb = 0; jb < 32; jb += 4) {
      const int j = jb + jq;
      const int srow = sidx[j];
      const float4 kv = *(const float4*)(kb + (size_t)srow * HDn + h * DKn + d16 * 4);
      float p = kv.x * qv.x + kv.y * qv.y + kv.z * qv.z + kv.w * qv.w;
      p += __shfl_xor(p, 1);
      p += __shfl_xor(p, 2);
      p += __shfl_xor(p, 4);
      p += __shfl_xor(p, 8);
      if (j < SKn) { mx = fmaxf(mx, p); sum += p; }
    }
    mx = fmaxf(mx, __shfl_xor(mx, 16));
    mx = fmaxf(mx, __shfl_xor(mx, 32));
    sum += __shfl_xor(sum, 16);
    sum += __shfl_xor(sum, 32);
    if (lane == 0) Mt[((size_t)(b * Hn + h)) * Tn + t] = mx - sum * (1.0f / SKn);
  }
}

// ------------- fused: blocks 0..31 top-30 per (b,h); blocks 32..35 vmean+base per b -------------
__global__ __launch_bounds__(256) void topk_vmean_base_kernel(
    const float* __restrict__ Mt, const float* __restrict__ v,
    const float* __restrict__ Wo, const float* __restrict__ bo,
    int* __restrict__ top, float* __restrict__ vmean, float* __restrict__ basep) {
  const int tid = threadIdx.x;
  const int lane = tid & 63, w = tid >> 6;
  __shared__ float vals[Tn];
  __shared__ float wv[4];
  __shared__ int wi[4];
  __shared__ float4 part[256];
  __shared__ float vm[HDn];

  if (blockIdx.x < 32) {
    const int bh = blockIdx.x;
    for (int i = tid; i < Tn; i += 256) vals[i] = Mt[(size_t)bh * Tn + i];
    __syncthreads();
    for (int u = 0; u < Un; ++u) {
      float bv = -1e30f; int bi = 0x7fffffff;
      for (int i = tid; i < Tn; i += 256) {
        const float x = vals[i];
        if (x > bv) { bv = x; bi = i; }
      }
#pragma unroll
      for (int o = 1; o < 64; o <<= 1) {
        const float ov = __shfl_xor(bv, o);
        const int oi = __shfl_xor(bi, o);
        if (ov > bv || (ov == bv && oi < bi)) { bv = ov; bi = oi; }
      }
      if (lane == 0) { wv[w] = bv; wi[w] = bi; }
      __syncthreads();
      bv = wv[0]; bi = wi[0];
#pragma unroll
      for (int j = 1; j < 4; ++j) {
        if (wv[j] > bv || (wv[j] == bv && wi[j] < bi)) { bv = wv[j]; bi = wi[j]; }
      }
      if (tid == 0) { top[bh * Un + u] = bi; vals[bi] = -1e30f; }
      __syncthreads();
    }
  } else {
    const int b = blockIdx.x - 32;
    const float4* v4 = (const float4*)(v + (size_t)b * Sn * HDn);
    const int c4 = tid & 127, half = tid >> 7;
    float4 acc = make_float4(0.f, 0.f, 0.f, 0.f);
    for (int s = half; s < Sn; s += 2) {
      const float4 x = v4[(size_t)s * 128 + c4];
      acc.x += x.x; acc.y += x.y; acc.z += x.z; acc.w += x.w;
    }
    part[tid] = acc;
    __syncthreads();
    if (half == 0) {
      float4 a = part[c4], bpp = part[128 + c4];
      const float sc = 1.0f / Sn;
      float4 r = make_float4((a.x + bpp.x) * sc, (a.y + bpp.y) * sc,
                             (a.z + bpp.z) * sc, (a.w + bpp.w) * sc);
      *(float4*)(vm + c4 * 4) = r;
      *(float4*)(vmean + b * HDn + c4 * 4) = r;
    }
    __syncthreads();
    const float4* Wo4 = (const float4*)Wo;
    float4 acc2 = make_float4(0.f, 0.f, 0.f, 0.f);
    for (int c = half * 256; c < half * 256 + 256; ++c) {
      const float vmc = vm[c];
      const float4 wrow = Wo4[(size_t)c * 128 + c4];
      acc2.x += vmc * wrow.x; acc2.y += vmc * wrow.y;
      acc2.z += vmc * wrow.z; acc2.w += vmc * wrow.w;
    }
    __syncthreads();
    part[tid] = acc2;
    __syncthreads();
    if (half == 0) {
      float4 a = part[c4], bpp = part[128 + c4];
      const float4 bb = ((const float4*)bo)[c4];
      float4 r = make_float4(a.x + bpp.x + bb.x, a.y + bpp.y + bb.y,
                             a.z + bpp.z + bb.z, a.w + bpp.w + bb.w);
      ((float4*)basep)[b * 128 + c4] = r;
    }
  }
}

// ------------- mega B: [0,160) grouped attn; [160,1184) out-base fill; [1184,3232) fscores tail fill -------------
__global__ __launch_bounds__(256) void attn_out_kernel(
    const float* __restrict__ q, const float* __restrict__ k,
    const float* __restrict__ v, const float* __restrict__ vmean,
    const int* __restrict__ top, const float* __restrict__ Wo,
    const float* __restrict__ basep,
    float* __restrict__ out, float* __restrict__ fscores) {
  const int tid = threadIdx.x;
  const int bid = blockIdx.x;

  if (bid >= NAttnG + NOutF) {
    // fscores tail fill (rows [RowSplit, 65536)), skip selected rows
    const int fid = bid - NAttnG - NOutF;       // 0..2047
    const int r = RowSplit + fid * 4;
    const int bh = r >> 11;
    const int tbase = r & (Tn - 1);
    __shared__ int sflag4[4];
    if (tid < 4) sflag4[tid] = 0;
    __syncthreads();
    if (tid < Un) {
      const int d = top[bh * Un + tid] - tbase;
      if (d >= 0 && d < 4) sflag4[d] = 1;
    }
    __syncthreads();
    const float c = 1.0f / Sn;
    const float4 c4v = make_float4(c, c, c, c);
    float4* fs4 = (float4*)fscores + (size_t)r * (Sn / 4);
#pragma unroll
    for (int rr = 0; rr < 4; ++rr) {
      if (!sflag4[rr]) {
        float4* row = fs4 + rr * (Sn / 4);
        row[tid] = c4v;
        row[256 + tid] = c4v;
      }
    }
    return;
  }

  if (bid >= NAttnG) {
    // out base fill: 8 rows; plain store unless row is selected (then atomicAdd)
    const int fid = bid - NAttnG;               // 0..1023
    const int r0 = fid * 8;
    const int b = r0 >> 11;
    const int t0 = r0 & (Tn - 1);
    __shared__ int sflag8[8];
    if (tid < 8) sflag8[tid] = 0;
    __syncthreads();
    if (tid < Hn * Un) {                        // 240 entries for this b
      const int d = top[b * Hn * Un + tid] - t0;
      if (d >= 0 && d < 8) sflag8[d] = 1;
    }
    __syncthreads();
    const int col4 = tid & 127, rh = tid >> 7;
    const float4 bv4 = ((const float4*)basep)[b * 128 + col4];
#pragma unroll
    for (int rp = 0; rp < 4; ++rp) {
      const int rr = rp * 2 + rh;
      float4* orow4 = (float4*)(out + (size_t)(r0 + rr) * HDn) + col4;
      if (sflag8[rr]) {
        float* p = (float*)orow4;
        atomicAdd(p + 0, bv4.x); atomicAdd(p + 1, bv4.y);
        atomicAdd(p + 2, bv4.z); atomicAdd(p + 3, bv4.w);
      } else {
        *orow4 = bv4;
      }
    }
    return;
  }

  // ---- grouped attention: Gu=6 u's per block, k/v read once per block ----
  const int grp = bid % NGroups;       // 0..4
  const int bh = bid / NGroups;        // 0..31
  const int h = bh & (Hn - 1), b = bh >> 3;
  const int u0 = grp * Gu;
  const int lane = tid & 63, w = tid >> 6;

  __shared__ float qs[Gu][DKn];        // reused later as delta
  __shared__ float sc[Gu][2052];       // padded: conflict-free column access
  __shared__ float red[8];
  __shared__ int tsel[Gu];
  __shared__ float4 partv[4][Gu][16];

  if (tid < Gu) tsel[tid] = top[bh * Un + u0 + tid];
  __syncthreads();
  for (int i = tid; i < Gu * DKn; i += 256) {
    const int g = i >> 6, d = i & 63;
    qs[g][d] = q[((size_t)(b * Tn + tsel[g])) * HDn + h * DKn + d];
  }
  __syncthreads();

  // phase 1: scores for all 6 u's, k row read once
  const float4* k4 = (const float4*)k;
  for (int s = tid; s < Sn; s += 256) {
    const float4* krow = k4 + ((size_t)(b * Sn + s)) * 128 + h * 16;
    float acc[Gu];
#pragma unroll
    for (int g = 0; g < Gu; ++g) acc[g] = 0.f;
#pragma unroll
    for (int d4i = 0; d4i < 16; ++d4i) {
      const float4 kv = krow[d4i];
#pragma unroll
      for (int g = 0; g < Gu; ++g) {
        const float4 qv = *(const float4*)&qs[g][d4i * 4];
        acc[g] += kv.x * qv.x + kv.y * qv.y + kv.z * qv.z + kv.w * qv.w;
      }
    }
#pragma unroll
    for (int g = 0; g < Gu; ++g) sc[g][s] = acc[g] * kScale;
  }
  __syncthreads();

  // phase 2: softmax per u
  float invs[Gu];
#pragma unroll
  for (int g = 0; g < Gu; ++g) {
    float lm = -1e30f;
    for (int i = tid; i < Sn; i += 256) lm = fmaxf(lm, sc[g][i]);
#pragma unroll
    for (int o = 1; o < 64; o <<= 1) lm = fmaxf(lm, __shfl_xor(lm, o));
    if (lane == 0) red[w] = lm;
    __syncthreads();
    const float mx = fmaxf(fmaxf(red[0], red[1]), fmaxf(red[2], red[3]));
    float ls = 0.f;
    for (int i = tid; i < Sn; i += 256) {
      const float e = __expf(sc[g][i] - mx);
      sc[g][i] = e;
      ls += e;
    }
#pragma unroll
    for (int o = 1; o < 64; o <<= 1) ls += __shfl_xor(ls, o);
    if (lane == 0) red[4 + w] = ls;
    __syncthreads();
    invs[g] = 1.0f / (red[4] + red[5] + red[6] + red[7]);
    __syncthreads();   // WAR on red[] before next g
  }
  // normalize + write fscores rows
#pragma unroll
  for (int g = 0; g < Gu; ++g) {
    const float inv = invs[g];
    float4* scg4 = (float4*)sc[g];
    float4* fsrow4 = (float4*)(fscores + ((size_t)bh * Tn + tsel[g]) * Sn);
#pragma unroll
    for (int it = 0; it < 2; ++it) {
      const int i = it * 256 + tid;
      float4 p = scg4[i];
      p.x *= inv; p.y *= inv; p.z *= inv; p.w *= inv;
      scg4[i] = p;
      fsrow4[i] = p;
    }
  }
  __syncthreads();

  // phase 3: attn = scores @ v, v row read once
  const int d4 = lane & 15;
  const int sg = (w << 2) + (lane >> 4);   // 0..15
  const float4* v4 = (const float4*)v;
  float4 pacc[Gu];
#pragma unroll
  for (int g = 0; g < Gu; ++g) pacc[g] = make_float4(0.f, 0.f, 0.f, 0.f);
  for (int s = sg; s < Sn; s += 16) {
    const float4 vv = v4[((size_t)(b * Sn + s)) * 128 + h * 16 + d4];
#pragma unroll
    for (int g = 0; g < Gu; ++g) {
      const float p = sc[g][s];
      pacc[g].x += p * vv.x; pacc[g].y += p * vv.y;
      pacc[g].z += p * vv.z; pacc[g].w += p * vv.w;
    }
  }
#pragma unroll
  for (int g = 0; g < Gu; ++g) {
#pragma unroll
    for (int o = 16; o < 64; o <<= 1) {
      pacc[g].x += __shfl_xor(pacc[g].x, o);
      pacc[g].y += __shfl_xor(pacc[g].y, o);
      pacc[g].z += __shfl_xor(pacc[g].z, o);
      pacc[g].w += __shfl_xor(pacc[g].w, o);
    }
    if (lane < 16) partv[w][g][lane] = pacc[g];
  }
  __syncthreads();
  if (tid < Gu * 16) {
    const int g = tid >> 4, dd = tid & 15;
    float4 r = partv[0][g][dd];
    const float4 r1 = partv[1][g][dd], r2 = partv[2][g][dd], r3 = partv[3][g][dd];
    r.x += r1.x + r2.x + r3.x; r.y += r1.y + r2.y + r3.y;
    r.z += r1.z + r2.z + r3.z; r.w += r1.w + r2.w + r3.w;
    const float4 vm4 = ((const float4*)vmean)[bh * 16 + dd];
    r.x -= vm4.x; r.y -= vm4.y; r.z -= vm4.z; r.w -= vm4.w;
    *(float4*)&qs[g][dd * 4] = r;      // qs reused as delta
  }
  __syncthreads();

  // phase 4: out rows += delta @ Wo[h*64:(h+1)*64,:], 2 u's in parallel
  const int col4 = tid & 127, gg = tid >> 7;
  const float4* Wo4 = (const float4*)Wo;
#pragma unroll
  for (int gp = 0; gp < Gu / 2; ++gp) {
    const int g = gp * 2 + gg;
    float4 a = make_float4(0.f, 0.f, 0.f, 0.f);
#pragma unroll
    for (int d = 0; d < DKn; ++d) {
      const float dv = qs[g][d];
      const float4 wrow = Wo4[(size_t)(h * DKn + d) * 128 + col4];
      a.x += dv * wrow.x; a.y += dv * wrow.y;
      a.z += dv * wrow.z; a.w += dv * wrow.w;
    }
    float* orow = out + ((size_t)(b * Tn + tsel[g])) * HDn + col4 * 4;
    atomicAdd(orow + 0, a.x); atomicAdd(orow + 1, a.y);
    atomicAdd(orow + 2, a.z); atomicAdd(orow + 3, a.w);
  }
}

extern "C" void kernel_launch(void* const* d_in, const int* in_sizes, int n_in,
                              void* d_out, int out_size, void* d_ws, size_t ws_size,
                              hipStream_t stream) {
  const float* x_q = (const float*)d_in[0];
  const float* x_k = (const float*)d_in[1];
  const float* x_v = (const float*)d_in[2];
  const float* Wq = (const float*)d_in[3];
  const float* bq = (const float*)d_in[4];
  const float* Wk = (const float*)d_in[5];
  const float* bk = (const float*)d_in[6];
  const float* Wv = (const float*)d_in[7];
  const float* bv = (const float*)d_in[8];
  const float* Wo = (const float*)d_in[9];
  const float* bo = (const float*)d_in[10];
  const int* idx = (const int*)d_in[11];

  float* out = (float*)d_out;
  float* fscores = out + (size_t)Bn * Tn * HDn;

  float* ws = (float*)d_ws;
  float* q = ws;
  float* kp = ws + (size_t)4194304;
  float* vp = ws + (size_t)8388608;
  float* Mt = ws + (size_t)12582912;
  float* vmean = ws + (size_t)12648448;
  float* basep = ws + (size_t)12650496;
  int* top = (int*)(ws + (size_t)12652544);

  // 1) fused q/k/v projections overlapped with most of the final_scores fill
  gemm_fill_kernel<<<NGemm + NFillA, 256, 0, stream>>>(
      x_q, x_k, x_v, Wq, Wk, Wv, bq, bk, bv, q, kp, vp, fscores);

  // 2) sampled scores -> M
  sampled_m_kernel<<<Bn * Tn, 64, 0, stream>>>(q, kp, idx, Mt);

  // 3) fused top-30 + v_mean + base row
  topk_vmean_base_kernel<<<36, 256, 0, stream>>>(Mt, vp, Wo, bo, top, vmean, basep);

  // 4) grouped attention + out base fill + fscores tail fill
  attn_out_kernel<<<NAttnG + NOutF + NTailF, 256, 0, stream>>>(
      q, kp, vp, vmean, top, Wo, basep, out, fscores);
}